// Round 9
// baseline (593.233 us; speedup 1.0000x reference)
//
#include <hip/hip_runtime.h>
#include <stdint.h>

#define BB   4
#define NN   100000
#define TOTAL (BB * NN)
#define DIN  16
#define DF   19          // 16 features + 3 voxel deltas
#define KO   128         // MLP width
#define GX   468
#define GY   468
#define VOL  (GX * GY)   // z-dim is 1
#define NV   (BB * VOL)  // 876096 output voxel rows (divisible by 64)
#define CAP  12          // max points kept per voxel (Poisson lambda~0.19)
#define SLOT_F 20        // floats per packed slot (19 + pad, 80B, 16B-aligned)
#define NWAVES (NV / 64) // 13689 output windows of 64 rows
#define OUT_F4 (NV * (KO / 4))         // 28,035,072 float4s (448.56 MB), fits u32
#define FPT   4                        // float4 stores per fill thread (64B)
#define FILLB (OUT_F4 / (256 * FPT))   // 27378 fill blocks, 4 float4s/thread
#define BINB  ((TOTAL + 255) / 256)    // 1563 bin blocks (dispatched FIRST)

typedef float vfloat2 __attribute__((ext_vector_type(2)));

// ---- workspace layout (float/int32 slots) ----
#define WS_COUNTS   0                      // NV ints
#define WS_FLAG     (NV)                   // 1 int
#define WS_PACKED   (NV + 16)              // NV*CAP*SLOT_F floats (~841MB)

// ---------------------------------------------------------------------------
// vx_prep: zero the 3.5MB counts array (one int4 per thread); block 0 detects
// point_mask element size (bool may arrive as uint8 / int32 / float32).
// Must precede the bin role's atomicAdd on counts.
// ---------------------------------------------------------------------------
__global__ __launch_bounds__(256) void vx_prep(
    int4* __restrict__ counts4,      // NV/4 int4s
    const uint4* __restrict__ mask_words,
    int* __restrict__ flag)
{
    if (blockIdx.x == 0) {
        __shared__ int sA, sB;
        if (threadIdx.x == 0) { sA = 0; sB = 0; }
        __syncthreads();
        int a = 0, b = 0;
        #pragma unroll
        for (int it = 0; it < 4; ++it) {
            uint4 w = mask_words[it * 256 + threadIdx.x];
            unsigned lo = (w.x & 0xFFu) | (w.y & 0xFFu) | (w.z & 0xFFu) | (w.w & 0xFFu);
            unsigned hi = (w.x & 0xFFFFFF00u) | (w.y & 0xFFFFFF00u) |
                          (w.z & 0xFFFFFF00u) | (w.w & 0xFFFFFF00u);
            if (hi) a = 1;
            if (lo) b = 1;
        }
        if (a) atomicOr(&sA, 1);
        if (b) atomicOr(&sB, 1);
        __syncthreads();
        if (threadIdx.x == 0) flag[0] = (sA && sB) ? 1 : 4;
    }
    const unsigned i = blockIdx.x * 256 + threadIdx.x;
    if (i < NV / 4) counts4[i] = make_int4(0, 0, 0, 0);
}

// ---------------------------------------------------------------------------
// vx_stage: one dispatch, two concurrent roles over disjoint memory.
//   blocks [0, BINB)            : BIN — per point -> voxel id; claim a slot
//     via atomicAdd on the L2-resident counts array; write the 19-float
//     feature vector directly into the slot. Latency-bound, ~26 MB of
//     scattered traffic. Dispatched FIRST so these blocks occupy CUs during
//     the fill ramp and retire in the store stream's shadow.
//   blocks [BINB, BINB+FILLB)   : FILL — sliding-front zero-fill of the
//     whole output: 4 consecutive float4 stores per thread (64B), huge grid
//     => resident blocks form a compact write-front (R6 evidence: this
//     schedule family is the best HIP fill measured, vs grid-stride ~3TB/s).
// No ordering is needed between the roles within the dispatch.
// ---------------------------------------------------------------------------
__global__ __launch_bounds__(256) void vx_stage(
    float4* __restrict__ out4,       // OUT_F4 float4s
    const float* __restrict__ xyz,
    const float* __restrict__ pfeat,
    const unsigned char* __restrict__ mask_raw,
    const int* __restrict__ flag,
    int* __restrict__ counts,
    float* __restrict__ packed)
{
    const unsigned b = blockIdx.x;
    if (b >= (unsigned)BINB) {
        // ---- fill role: 4 consecutive float4 zero-stores per thread ----
        const unsigned base = ((b - BINB) * 256 + threadIdx.x) * FPT;
        const float4 zf = make_float4(0.f, 0.f, 0.f, 0.f);
        #pragma unroll
        for (int k = 0; k < FPT; ++k) {
            const unsigned idx = base + k;
            if (idx < (unsigned)OUT_F4) out4[idx] = zf;
        }
        return;
    }
    // ---- bin role ----
    const int p = (int)(b * 256 + threadIdx.x);
    if (p >= TOTAL) return;
    const float x = xyz[p * 3 + 0];
    const float y = xyz[p * 3 + 1];
    const float z = xyz[p * 3 + 2];
    bool m;
    if (flag[0] == 4) m = (((const int*)mask_raw)[p] != 0);
    else              m = (mask_raw[p] != 0);
    const float fx = floorf(x / 0.32f);
    const float fy = floorf(y / 0.32f);
    const float fz = floorf(z / 6.0f);
    const int ix = (int)fx + 234;
    const int iy = (int)fy + 234;
    const int iz = (int)fz + 1;
    const bool inb = ((unsigned)ix < (unsigned)GX) &
                     ((unsigned)iy < (unsigned)GY) &
                     (iz == 0) & m;
    if (!inb) return;
    const int vid = (p / NN) * VOL + ix * GY + iy;
    const int rank = atomicAdd(&counts[vid], 1);
    if (rank >= CAP) return;

    float4* slot = (float4*)(packed + (size_t)(vid * CAP + rank) * SLOT_F);
    const float4* pf4 = (const float4*)(pfeat + (size_t)p * DIN);
    slot[0] = pf4[0];
    slot[1] = pf4[1];
    slot[2] = pf4[2];
    slot[3] = pf4[3];
    slot[4] = make_float4(x - fx * 0.32f, y - fy * 0.32f, z - fz * 6.0f, 0.f);
}

// ---------------------------------------------------------------------------
// vx_write: one wave per 64 consecutive voxels; ONLY occupied rows (~17%)
// are computed and stored (empty rows already zeroed by the fill role).
// Bit-scan walk with 1-deep prefetch of the next row's packed slot (91% of
// occupied rows have exactly 1 point). NT stores: avoid evicting the packed
// slots being gathered from L2 (R3 evidence: plain stores here regressed).
// ---------------------------------------------------------------------------
__global__ __launch_bounds__(256) void vx_write(
    const float* __restrict__ W,       // [19,128]
    const float* __restrict__ bias,    // [128]
    const int* __restrict__ counts,
    const float* __restrict__ packed,
    float* __restrict__ out)           // [NV,128]
{
    const int lane = threadIdx.x & 63;
    const int wid  = (blockIdx.x * 256 + threadIdx.x) >> 6;
    if (wid >= NWAVES) return;
    const int v0 = wid * 64;

    const int c_mine = counts[v0 + lane];            // coalesced 256B load
    const unsigned long long occ = __ballot(c_mine > 0);
    if (!occ) return;

    const float2* W2 = (const float2*)W;             // [19][64]
    float2 w[DF];
    #pragma unroll
    for (int d = 0; d < DF; ++d) w[d] = W2[d * 64 + lane];
    const float2 bb = ((const float2*)bias)[lane];

    vfloat2* dst0 = (vfloat2*)(out + (size_t)v0 * KO) + lane;

    unsigned long long rem = occ;
    int j_cur = __builtin_ctzll(rem);
    rem &= rem - 1;
    float4 q0, q1, q2, q3, q4;
    {
        const float4* base = (const float4*)(packed +
                             (size_t)(v0 + j_cur) * CAP * SLOT_F);
        q0 = base[0]; q1 = base[1]; q2 = base[2]; q3 = base[3]; q4 = base[4];
    }
    while (j_cur >= 0) {
        // prefetch first point of the NEXT occupied row
        int j_nxt = -1;
        float4 n0, n1, n2, n3, n4;
        if (rem) {
            j_nxt = __builtin_ctzll(rem);
            rem &= rem - 1;
            const float4* nb = (const float4*)(packed +
                               (size_t)(v0 + j_nxt) * CAP * SLOT_F);
            n0 = nb[0]; n1 = nb[1]; n2 = nb[2]; n3 = nb[3]; n4 = nb[4];
        }

        const int c = min(__shfl(c_mine, j_cur), CAP);
        const float4* base = (const float4*)(packed +
                             (size_t)(v0 + j_cur) * CAP * SLOT_F);
        float m0 = -3.0e38f, m1 = -3.0e38f;
        for (int t = 0; t < c; ++t) {
            float4 p0, p1, p2, p3, p4;
            if (t == 0) { p0 = q0; p1 = q1; p2 = q2; p3 = q3; p4 = q4; }
            else {
                p0 = base[t * 5 + 0]; p1 = base[t * 5 + 1];
                p2 = base[t * 5 + 2]; p3 = base[t * 5 + 3];
                p4 = base[t * 5 + 4];
            }
            float a0 = bb.x, a1 = bb.y;
            a0 = fmaf(p0.x, w[0].x, a0);  a1 = fmaf(p0.x, w[0].y, a1);
            a0 = fmaf(p0.y, w[1].x, a0);  a1 = fmaf(p0.y, w[1].y, a1);
            a0 = fmaf(p0.z, w[2].x, a0);  a1 = fmaf(p0.z, w[2].y, a1);
            a0 = fmaf(p0.w, w[3].x, a0);  a1 = fmaf(p0.w, w[3].y, a1);
            a0 = fmaf(p1.x, w[4].x, a0);  a1 = fmaf(p1.x, w[4].y, a1);
            a0 = fmaf(p1.y, w[5].x, a0);  a1 = fmaf(p1.y, w[5].y, a1);
            a0 = fmaf(p1.z, w[6].x, a0);  a1 = fmaf(p1.z, w[6].y, a1);
            a0 = fmaf(p1.w, w[7].x, a0);  a1 = fmaf(p1.w, w[7].y, a1);
            a0 = fmaf(p2.x, w[8].x, a0);  a1 = fmaf(p2.x, w[8].y, a1);
            a0 = fmaf(p2.y, w[9].x, a0);  a1 = fmaf(p2.y, w[9].y, a1);
            a0 = fmaf(p2.z, w[10].x, a0); a1 = fmaf(p2.z, w[10].y, a1);
            a0 = fmaf(p2.w, w[11].x, a0); a1 = fmaf(p2.w, w[11].y, a1);
            a0 = fmaf(p3.x, w[12].x, a0); a1 = fmaf(p3.x, w[12].y, a1);
            a0 = fmaf(p3.y, w[13].x, a0); a1 = fmaf(p3.y, w[13].y, a1);
            a0 = fmaf(p3.z, w[14].x, a0); a1 = fmaf(p3.z, w[14].y, a1);
            a0 = fmaf(p3.w, w[15].x, a0); a1 = fmaf(p3.w, w[15].y, a1);
            a0 = fmaf(p4.x, w[16].x, a0); a1 = fmaf(p4.x, w[16].y, a1);
            a0 = fmaf(p4.y, w[17].x, a0); a1 = fmaf(p4.y, w[17].y, a1);
            a0 = fmaf(p4.z, w[18].x, a0); a1 = fmaf(p4.z, w[18].y, a1);
            m0 = fmaxf(m0, a0);
            m1 = fmaxf(m1, a1);
        }
        // relu(max) == max(relu) (monotone)
        vfloat2 rv = {fmaxf(m0, 0.f), fmaxf(m1, 0.f)};
        __builtin_nontemporal_store(rv, dst0 + (size_t)j_cur * 64);

        j_cur = j_nxt;
        q0 = n0; q1 = n1; q2 = n2; q3 = n3; q4 = n4;
    }
}

extern "C" void kernel_launch(void* const* d_in, const int* in_sizes, int n_in,
                              void* d_out, int out_size, void* d_ws, size_t ws_size,
                              hipStream_t stream) {
    const float* xyz   = (const float*)d_in[0];
    const float* pfeat = (const float*)d_in[1];
    const unsigned char* mask = (const unsigned char*)d_in[2];
    const float* W     = (const float*)d_in[3];
    const float* bias  = (const float*)d_in[4];
    float* out = (float*)d_out;
    int* ws = (int*)d_ws;

    int*   counts = ws + WS_COUNTS;
    int*   flag   = ws + WS_FLAG;
    float* packed = (float*)(ws + WS_PACKED);

    vx_prep<<<(NV / 4 + 255) / 256, 256, 0, stream>>>((int4*)counts,
                                                      (const uint4*)mask, flag);
    vx_stage<<<BINB + FILLB, 256, 0, stream>>>((float4*)out, xyz, pfeat,
                                               mask, flag, counts, packed);
    vx_write<<<(NWAVES + 3) / 4, 256, 0, stream>>>(W, bias, counts,
                                                   packed, out);
}

// Round 10
// 526.883 us; speedup vs baseline: 1.1259x; 1.1259x over previous
//
#include <hip/hip_runtime.h>
#include <stdint.h>

#define BB   4
#define NN   100000
#define TOTAL (BB * NN)
#define DIN  16
#define DF   19          // 16 features + 3 voxel deltas
#define KO   128         // MLP width
#define GX   468
#define GY   468
#define VOL  (GX * GY)   // z-dim is 1
#define NV   (BB * VOL)  // 876096 output voxel rows (divisible by 64)
#define CAP  12          // max points kept per voxel (Poisson lambda~0.19)
#define SLOT_F 20        // floats per packed slot (19 + pad, 80B, 16B-aligned)
#define NWAVES (NV / 64) // 13689 output windows of 64 rows
#define OUT_F4 (NV * (KO / 4))         // 28,035,072 float4s (448.56 MB), fits u32
#define FILLB (OUT_F4 / 256)           // 109512 blocks, one float4 per thread
#define CNTB  ((NV / 4 + 255) / 256)   // 856 blocks for the counts array

typedef float vfloat2 __attribute__((ext_vector_type(2)));

// ---- workspace layout (float/int32 slots) ----
#define WS_COUNTS   0                      // NV ints
#define WS_FLAG     (NV)                   // 1 int
#define WS_PACKED   (NV + 16)              // NV*CAP*SLOT_F floats (~841MB)

// ---------------------------------------------------------------------------
// fill_prep: rocclr-schedule fill. ONE 16B store per thread, huge grid —
// resident blocks form a compact sliding write-front through the buffer
// (high DRAM page locality), unlike a 2048-block grid-stride loop whose
// 2048 fronts thrash pages at ~2.5-3 TB/s (R1/R5 accounting; rocclr's
// identical-pattern fill hits 6.3 TB/s in the same captures).
// Blocks [0, FILLB): zero the output. Blocks [FILLB, FILLB+CNTB): zero
// counts. Block 0 also detects point_mask element size.
// This exact kernel measured 529.8 µs total (R6) — best of 7 structures;
// overlap variants (R2/R9) and cooperative (R4) all regressed.
// ---------------------------------------------------------------------------
__global__ __launch_bounds__(256) void fill_prep(
    float4* __restrict__ out4,       // OUT_F4 float4s
    int4* __restrict__ counts4,      // NV/4 int4s
    const uint4* __restrict__ mask_words,
    int* __restrict__ flag)
{
    const unsigned b = blockIdx.x;
    if (b == 0) {
        __shared__ int sA, sB;
        if (threadIdx.x == 0) { sA = 0; sB = 0; }
        __syncthreads();
        int a = 0, c = 0;
        #pragma unroll
        for (int it = 0; it < 4; ++it) {
            uint4 w = mask_words[it * 256 + threadIdx.x];
            unsigned lo = (w.x & 0xFFu) | (w.y & 0xFFu) | (w.z & 0xFFu) | (w.w & 0xFFu);
            unsigned hi = (w.x & 0xFFFFFF00u) | (w.y & 0xFFFFFF00u) |
                          (w.z & 0xFFFFFF00u) | (w.w & 0xFFFFFF00u);
            if (hi) a = 1;
            if (lo) c = 1;
        }
        if (a) atomicOr(&sA, 1);
        if (c) atomicOr(&sB, 1);
        __syncthreads();
        if (threadIdx.x == 0) flag[0] = (sA && sB) ? 1 : 4;
    }
    if (b < (unsigned)FILLB) {
        out4[b * 256 + threadIdx.x] = make_float4(0.f, 0.f, 0.f, 0.f);
    } else {
        const unsigned i = (b - FILLB) * 256 + threadIdx.x;
        if (i < NV / 4) counts4[i] = make_int4(0, 0, 0, 0);
    }
}

// ---------------------------------------------------------------------------
// pass1: per point -> voxel id; claim a slot via atomicAdd on the L2-resident
// counts array, and write the point's 19-float feature vector DIRECTLY into
// the slot (no pointer-chasing in the write kernel).
// ---------------------------------------------------------------------------
__global__ __launch_bounds__(256) void pass1_bin(
    const float* __restrict__ xyz,
    const float* __restrict__ pfeat,
    const unsigned char* __restrict__ mask_raw,
    const int* __restrict__ flag,
    int* __restrict__ counts,
    float* __restrict__ packed)
{
    const int p = blockIdx.x * 256 + threadIdx.x;
    if (p >= TOTAL) return;
    const float x = xyz[p * 3 + 0];
    const float y = xyz[p * 3 + 1];
    const float z = xyz[p * 3 + 2];
    bool m;
    if (flag[0] == 4) m = (((const int*)mask_raw)[p] != 0);
    else              m = (mask_raw[p] != 0);
    const float fx = floorf(x / 0.32f);
    const float fy = floorf(y / 0.32f);
    const float fz = floorf(z / 6.0f);
    const int ix = (int)fx + 234;
    const int iy = (int)fy + 234;
    const int iz = (int)fz + 1;
    const bool inb = ((unsigned)ix < (unsigned)GX) &
                     ((unsigned)iy < (unsigned)GY) &
                     (iz == 0) & m;
    if (!inb) return;
    const int vid = (p / NN) * VOL + ix * GY + iy;
    const int rank = atomicAdd(&counts[vid], 1);
    if (rank >= CAP) return;

    float4* slot = (float4*)(packed + (size_t)(vid * CAP + rank) * SLOT_F);
    const float4* pf4 = (const float4*)(pfeat + (size_t)p * DIN);
    slot[0] = pf4[0];
    slot[1] = pf4[1];
    slot[2] = pf4[2];
    slot[3] = pf4[3];
    slot[4] = make_float4(x - fx * 0.32f, y - fy * 0.32f, z - fz * 6.0f, 0.f);
}

// ---------------------------------------------------------------------------
// write_occ: one wave per 64 consecutive voxels; ONLY occupied rows (~17%)
// are computed and stored (empty rows already zeroed by fill_prep).
// Bit-scan walk with 1-deep prefetch of the next row's packed slot (91% of
// occupied rows have exactly 1 point). NT stores: avoid evicting the packed
// slots being gathered from L2 (R3 evidence: plain stores here regressed).
// ---------------------------------------------------------------------------
__global__ __launch_bounds__(256) void write_occ(
    const float* __restrict__ W,       // [19,128]
    const float* __restrict__ bias,    // [128]
    const int* __restrict__ counts,
    const float* __restrict__ packed,
    float* __restrict__ out)           // [NV,128]
{
    const int lane = threadIdx.x & 63;
    const int wid  = (blockIdx.x * 256 + threadIdx.x) >> 6;
    if (wid >= NWAVES) return;
    const int v0 = wid * 64;

    const int c_mine = counts[v0 + lane];            // coalesced 256B load
    const unsigned long long occ = __ballot(c_mine > 0);
    if (!occ) return;

    const float2* W2 = (const float2*)W;             // [19][64]
    float2 w[DF];
    #pragma unroll
    for (int d = 0; d < DF; ++d) w[d] = W2[d * 64 + lane];
    const float2 bb = ((const float2*)bias)[lane];

    vfloat2* dst0 = (vfloat2*)(out + (size_t)v0 * KO) + lane;

    unsigned long long rem = occ;
    int j_cur = __builtin_ctzll(rem);
    rem &= rem - 1;
    float4 q0, q1, q2, q3, q4;
    {
        const float4* base = (const float4*)(packed +
                             (size_t)(v0 + j_cur) * CAP * SLOT_F);
        q0 = base[0]; q1 = base[1]; q2 = base[2]; q3 = base[3]; q4 = base[4];
    }
    while (j_cur >= 0) {
        // prefetch first point of the NEXT occupied row
        int j_nxt = -1;
        float4 n0, n1, n2, n3, n4;
        if (rem) {
            j_nxt = __builtin_ctzll(rem);
            rem &= rem - 1;
            const float4* nb = (const float4*)(packed +
                               (size_t)(v0 + j_nxt) * CAP * SLOT_F);
            n0 = nb[0]; n1 = nb[1]; n2 = nb[2]; n3 = nb[3]; n4 = nb[4];
        }

        const int c = min(__shfl(c_mine, j_cur), CAP);
        const float4* base = (const float4*)(packed +
                             (size_t)(v0 + j_cur) * CAP * SLOT_F);
        float m0 = -3.0e38f, m1 = -3.0e38f;
        for (int t = 0; t < c; ++t) {
            float4 p0, p1, p2, p3, p4;
            if (t == 0) { p0 = q0; p1 = q1; p2 = q2; p3 = q3; p4 = q4; }
            else {
                p0 = base[t * 5 + 0]; p1 = base[t * 5 + 1];
                p2 = base[t * 5 + 2]; p3 = base[t * 5 + 3];
                p4 = base[t * 5 + 4];
            }
            float a0 = bb.x, a1 = bb.y;
            a0 = fmaf(p0.x, w[0].x, a0);  a1 = fmaf(p0.x, w[0].y, a1);
            a0 = fmaf(p0.y, w[1].x, a0);  a1 = fmaf(p0.y, w[1].y, a1);
            a0 = fmaf(p0.z, w[2].x, a0);  a1 = fmaf(p0.z, w[2].y, a1);
            a0 = fmaf(p0.w, w[3].x, a0);  a1 = fmaf(p0.w, w[3].y, a1);
            a0 = fmaf(p1.x, w[4].x, a0);  a1 = fmaf(p1.x, w[4].y, a1);
            a0 = fmaf(p1.y, w[5].x, a0);  a1 = fmaf(p1.y, w[5].y, a1);
            a0 = fmaf(p1.z, w[6].x, a0);  a1 = fmaf(p1.z, w[6].y, a1);
            a0 = fmaf(p1.w, w[7].x, a0);  a1 = fmaf(p1.w, w[7].y, a1);
            a0 = fmaf(p2.x, w[8].x, a0);  a1 = fmaf(p2.x, w[8].y, a1);
            a0 = fmaf(p2.y, w[9].x, a0);  a1 = fmaf(p2.y, w[9].y, a1);
            a0 = fmaf(p2.z, w[10].x, a0); a1 = fmaf(p2.z, w[10].y, a1);
            a0 = fmaf(p2.w, w[11].x, a0); a1 = fmaf(p2.w, w[11].y, a1);
            a0 = fmaf(p3.x, w[12].x, a0); a1 = fmaf(p3.x, w[12].y, a1);
            a0 = fmaf(p3.y, w[13].x, a0); a1 = fmaf(p3.y, w[13].y, a1);
            a0 = fmaf(p3.z, w[14].x, a0); a1 = fmaf(p3.z, w[14].y, a1);
            a0 = fmaf(p3.w, w[15].x, a0); a1 = fmaf(p3.w, w[15].y, a1);
            a0 = fmaf(p4.x, w[16].x, a0); a1 = fmaf(p4.x, w[16].y, a1);
            a0 = fmaf(p4.y, w[17].x, a0); a1 = fmaf(p4.y, w[17].y, a1);
            a0 = fmaf(p4.z, w[18].x, a0); a1 = fmaf(p4.z, w[18].y, a1);
            m0 = fmaxf(m0, a0);
            m1 = fmaxf(m1, a1);
        }
        // relu(max) == max(relu) (monotone)
        vfloat2 rv = {fmaxf(m0, 0.f), fmaxf(m1, 0.f)};
        __builtin_nontemporal_store(rv, dst0 + (size_t)j_cur * 64);

        j_cur = j_nxt;
        q0 = n0; q1 = n1; q2 = n2; q3 = n3; q4 = n4;
    }
}

extern "C" void kernel_launch(void* const* d_in, const int* in_sizes, int n_in,
                              void* d_out, int out_size, void* d_ws, size_t ws_size,
                              hipStream_t stream) {
    const float* xyz   = (const float*)d_in[0];
    const float* pfeat = (const float*)d_in[1];
    const unsigned char* mask = (const unsigned char*)d_in[2];
    const float* W     = (const float*)d_in[3];
    const float* bias  = (const float*)d_in[4];
    float* out = (float*)d_out;
    int* ws = (int*)d_ws;

    int*   counts = ws + WS_COUNTS;
    int*   flag   = ws + WS_FLAG;
    float* packed = (float*)(ws + WS_PACKED);

    fill_prep<<<FILLB + CNTB, 256, 0, stream>>>((float4*)out, (int4*)counts,
                                                (const uint4*)mask, flag);
    pass1_bin<<<(TOTAL + 255) / 256, 256, 0, stream>>>(xyz, pfeat, mask, flag,
                                                       counts, packed);
    write_occ<<<(NWAVES + 3) / 4, 256, 0, stream>>>(W, bias, counts,
                                                    packed, out);
}